// Round 4
// baseline (190.450 us; speedup 1.0000x reference)
//
#include <hip/hip_runtime.h>
#include <math.h>
#include <stdint.h>

// Problem constants (static per reference):
//   B=32, N_ATOMS=128, C=25 (rep 2,2,0), RADIUS=8, MAX_NEIGHBORS=32
#define NATOMS   128
#define NCELLS   25
#define NCAND    (NATOMS * NCELLS)   // 3200 candidates per center atom
#define MAXNB    32
#define R2       64.0f
#define BLK      256
#define NGRP     (NCAND / 4)         // 800 float4 groups along f = j*25+c
#define KEYCAP   256

// One block per (b,i) center atom. d2 is REGISTER-resident: thread t owns
// float4 groups {t, t+256, t+512} (+768+t for t<32), i.e. <=16 d2 values.
// No s_d2 array -> ~3.7 KB LDS, no LDS round-trip between compute/selection/
// store. Selection: fine histogram of d2 in [0,16) (32nd NN sits at d2~2.6),
// wave-shuffle prefix scan, exact stable cutoff key (d2 bits << 32 | flat f,
// matching jnp stable argsort tie-break) among the critical bin's members
// (expected ~1-2). Full-range histogram retry, and a bit-exact recompute-rank
// fallback if the key buffer ever overflows (never expected).
__global__ __launch_bounds__(BLK) void graph_kernel(
    const float* __restrict__ pos, const float* __restrict__ cell,
    float* __restrict__ out_dist, float* __restrict__ out_ctype,
    float* __restrict__ out_mask, float* __restrict__ out_nb)
{
    __shared__ float4 s_pos4[NATOMS];          // 1 ds_read_b128 per j
    __shared__ float4 s_off4[NCELLS];
    __shared__ float  s_ct[NCELLS];            // ctype LUT
    __shared__ unsigned s_hist[256];
    __shared__ unsigned s_wtot[4];
    __shared__ int s_wred[4];
    __shared__ unsigned long long s_keys[KEYCAP];
    __shared__ unsigned s_cnt;
    __shared__ int s_binsel, s_need, s_tot, s_att;
    __shared__ unsigned long long s_K;

    const int bi   = blockIdx.x;       // b*128 + i
    const int b    = bi >> 7;
    const int i    = bi & 127;
    const int tid  = threadIdx.x;
    const int lane = tid & 63;
    const int w    = tid >> 6;

    // ---- stage inputs into LDS (disjoint thread ranges) ----
    if (tid < NATOMS) {
        const float* p = pos + (b * NATOMS + tid) * 3;
        s_pos4[tid] = make_float4(p[0], p[1], p[2], 0.0f);
    }
    if (tid >= 160 && tid < 160 + NCELLS) {
        int c = tid - 160;
        float ux = (float)(c / 5 - 2);
        float uy = (float)(c % 5 - 2);
        // off = ux*row0 + uy*row1; products exact (|u|<=2), one rounded add.
        float ox = __fadd_rn(__fmul_rn(ux, cell[b*9+0]), __fmul_rn(uy, cell[b*9+3]));
        float oy = __fadd_rn(__fmul_rn(ux, cell[b*9+1]), __fmul_rn(uy, cell[b*9+4]));
        float oz = __fadd_rn(__fmul_rn(ux, cell[b*9+2]), __fmul_rn(uy, cell[b*9+5]));
        s_off4[c] = make_float4(ox, oy, oz, 0.0f);
        // ct = (ux+2)*5 + (uy+2)*5 (mults=[5,5,1] quirk per reference)
        s_ct[c] = (float)(5 * (c / 5) + 5 * (c % 5));
    }
    s_hist[tid] = 0u;
    if (tid == 0) { s_cnt = 0; s_binsel = -1; s_need = 0; s_att = 0; s_K = ~0ULL; }
    __syncthreads();

    const float4 ctr = s_pos4[i];      // LDS broadcast

    // ---- pass 1: d2 into registers, within count, fine histogram (d2<16) ----
    float d2r[16];
    int local = 0;
    #pragma unroll
    for (int k = 0; k < 4; k++) {
        int g = k * BLK + tid;
        if (g < NGRP) {
            int f0 = g * 4;
            int j = f0 / 25;           // compiler magic-div, once per group
            int c = f0 - j * 25;
            #pragma unroll
            for (int e = 0; e < 4; e++) {
                float4 p = s_pos4[j];
                float4 o = s_off4[c];
                // Replicate reference association exactly (no FMA contraction):
                float dx = __fadd_rn(__fsub_rn(p.x, ctr.x), o.x);
                float dy = __fadd_rn(__fsub_rn(p.y, ctr.y), o.y);
                float dz = __fadd_rn(__fsub_rn(p.z, ctr.z), o.z);
                float d2 = __fadd_rn(__fadd_rn(__fmul_rn(dx,dx), __fmul_rn(dy,dy)),
                                     __fmul_rn(dz,dz));
                bool within = (d2 <= R2) && (d2 > 1e-4f);
                d2r[k*4+e] = within ? d2 : __builtin_inff();
                if (within) {
                    local++;
                    if (d2 < 16.0f)
                        atomicAdd(&s_hist[(int)(d2 * 16.0f)], 1u);
                }
                c++; if (c == 25) { c = 0; j++; }
            }
        }
    }
    for (int o = 32; o; o >>= 1) local += __shfl_down(local, o);
    if (lane == 0) s_wred[w] = local;
    __syncthreads();
    if (tid == 0) {
        int tot = s_wred[0] + s_wred[1] + s_wred[2] + s_wred[3];
        s_tot = tot;
        // per-image clamped count; <=4096 per image -> exact float atomic sum
        atomicAdd(&out_nb[b], (float)(tot < MAXNB ? tot : MAXNB));
    }
    __syncthreads();

    if (s_tot > MAXNB) {
        // ---- find critical bin: attempt 0 = [0,16) fine (prebuilt),
        //      attempt 1 = full range [0,64] coarse (rare) ----
        for (int att = 0; att < 2 && s_binsel < 0; att++) {
            if (att == 1) {   // rebuild full-range histogram from registers
                s_hist[tid] = 0u;
                __syncthreads();
                #pragma unroll
                for (int k = 0; k < 4; k++) {
                    int g = k * BLK + tid;
                    if (g < NGRP) {
                        #pragma unroll
                        for (int e = 0; e < 4; e++) {
                            float d2 = d2r[k*4+e];
                            if (d2 < 64.5f) {
                                int bin = (int)(d2 * 4.0f);
                                if (bin > 255) bin = 255;
                                atomicAdd(&s_hist[bin], 1u);
                            }
                        }
                    }
                }
                __syncthreads();
            }
            // wave-shuffle inclusive scan of 256 bins (4 waves x 64 bins)
            unsigned h = s_hist[tid];
            int v = (int)h;
            #pragma unroll
            for (int off = 1; off < 64; off <<= 1) {
                int u = __shfl_up(v, off, 64);
                if (lane >= off) v += u;
            }
            if (lane == 63) s_wtot[w] = (unsigned)v;
            __syncthreads();
            unsigned pre = 0;
            for (int ww = 0; ww < w; ww++) pre += s_wtot[ww];
            unsigned htot = s_wtot[0] + s_wtot[1] + s_wtot[2] + s_wtot[3];
            unsigned ci = (unsigned)v + pre, ce = ci - h;
            if (htot >= MAXNB && h > 0 && ce < MAXNB && ci >= MAXNB) {
                s_binsel = tid;
                s_need   = MAXNB - (int)ce;
                s_att    = att;
            }
            __syncthreads();
        }

        // ---- exact cutoff key inside the critical bin (from registers) ----
        const int   binsel = s_binsel;
        const float sc  = s_att ? 4.0f  : 16.0f;
        const float lim = s_att ? 64.5f : 16.0f;
        #pragma unroll
        for (int k = 0; k < 4; k++) {
            int g = k * BLK + tid;
            if (g < NGRP) {
                int f0 = g * 4;
                #pragma unroll
                for (int e = 0; e < 4; e++) {
                    float d2 = d2r[k*4+e];
                    if (d2 < lim) {
                        int bin = (int)(d2 * sc);
                        if (bin > 255) bin = 255;
                        if (bin == binsel) {
                            unsigned idx = atomicAdd(&s_cnt, 1u);
                            if (idx < KEYCAP)
                                s_keys[idx] =
                                    ((unsigned long long)__float_as_uint(d2) << 32)
                                    | (unsigned)(f0 + e);
                        }
                    }
                }
            }
        }
        __syncthreads();
        const int m = (int)s_cnt, need = s_need;
        if (m <= KEYCAP) {
            for (int p = tid; p < m; p += BLK) {
                unsigned long long kp = s_keys[p];
                int r = 0;
                for (int q = 0; q < m; q++) r += (s_keys[q] < kp);
                if (r == need - 1) s_K = kp;   // keys distinct -> unique
            }
        } else {
            // Never-expected fallback: rank my critical-bin candidates by
            // bit-exact recompute of every candidate's d2 from staged inputs.
            #pragma unroll 1
            for (int k = 0; k < 4; k++) {
                int g = k * BLK + tid;
                if (g >= NGRP) continue;
                int f0 = g * 4;
                for (int e = 0; e < 4; e++) {
                    float d2 = d2r[k*4+e];
                    if (d2 >= lim) continue;
                    int bin = (int)(d2 * sc);
                    if (bin > 255) bin = 255;
                    if (bin != binsel) continue;
                    unsigned long long kf =
                        ((unsigned long long)__float_as_uint(d2) << 32)
                        | (unsigned)(f0 + e);
                    int r = 0;
                    for (int q = 0; q < NCAND; q++) {
                        int jq = q / 25, cq = q - (q / 25) * 25;
                        float4 p = s_pos4[jq];
                        float4 o = s_off4[cq];
                        float dx = __fadd_rn(__fsub_rn(p.x, ctr.x), o.x);
                        float dy = __fadd_rn(__fsub_rn(p.y, ctr.y), o.y);
                        float dz = __fadd_rn(__fsub_rn(p.z, ctr.z), o.z);
                        float dq = __fadd_rn(__fadd_rn(__fmul_rn(dx,dx),
                                                       __fmul_rn(dy,dy)),
                                             __fmul_rn(dz,dz));
                        bool within = (dq <= R2) && (dq > 1e-4f);
                        if (!within || dq >= lim) continue;
                        int bq = (int)(dq * sc);
                        if (bq > 255) bq = 255;
                        if (bq != binsel) continue;
                        unsigned long long kq =
                            ((unsigned long long)__float_as_uint(dq) << 32)
                            | (unsigned)q;
                        r += (kq < kf);
                    }
                    if (r == need - 1) s_K = kf;
                }
            }
        }
        __syncthreads();
    }
    const unsigned long long K = s_K;

    // ---- write outputs from registers (float4, coalesced) ----
    const long long base = (long long)bi * NCAND;
    float4* o0 = (float4*)(out_dist  + base);
    float4* o1 = (float4*)(out_ctype + base);
    float4* o2 = (float4*)(out_mask  + base);
    #pragma unroll
    for (int k = 0; k < 4; k++) {
        int g = k * BLK + tid;
        if (g < NGRP) {
            int f0 = g * 4;
            int j = f0 / 25;
            int c = f0 - j * 25;
            float4 r0, r1, r2;
            #pragma unroll
            for (int e = 0; e < 4; e++) {
                float d2 = d2r[k*4+e];
                bool within = (d2 <= R2);   // inf for non-within reconstructs mask
                unsigned long long key =
                    ((unsigned long long)__float_as_uint(d2) << 32)
                    | (unsigned)(f0 + e);
                bool keep = within && (key <= K);
                (&r0.x)[e] = keep ? sqrtf(d2) : 0.0f;
                (&r1.x)[e] = keep ? s_ct[c] : 0.0f;
                (&r2.x)[e] = keep ? 1.0f : 0.0f;
                c++; if (c == 25) c = 0;
            }
            o0[g] = r0; o1[g] = r1; o2[g] = r2;
        }
    }
}

extern "C" void kernel_launch(void* const* d_in, const int* in_sizes, int n_in,
                              void* d_out, int out_size, void* d_ws, size_t ws_size,
                              hipStream_t stream) {
    const float* pos  = (const float*)d_in[0];   // [32,128,3]
    const float* cell = (const float*)d_in[1];   // [32,3,3]
    float* out = (float*)d_out;
    const long long E = 32LL * NATOMS * NATOMS * NCELLS;   // 13,107,200
    float* out_dist  = out;
    float* out_ct    = out + E;
    float* out_mask  = out + 2 * E;
    float* out_nb    = out + 3 * E;                         // 32 floats

    // zero the 32 per-image counters (d_out is poisoned 0xAA), then accumulate
    // one clamped count per block via device-scope float atomics (exact: <=4096).
    hipMemsetAsync(out_nb, 0, 32 * sizeof(float), stream);
    hipLaunchKernelGGL(graph_kernel, dim3(32 * NATOMS), dim3(BLK), 0, stream,
                       pos, cell, out_dist, out_ct, out_mask, out_nb);
}